// Round 1
// baseline (80.045 us; speedup 1.0000x reference)
//
#include <hip/hip_runtime.h>
#include <hip/hip_cooperative_groups.h>

// mi = BETA * sum_d ( E[y_d^2] - (E[y_d])^2 )  over y: [1024, 256] fp32.
// Derivation: mean_i mean_j (y_jd - y_id)^2 = 2*Var_d; the /2 cancels.
//
// Fused single-dispatch version: the prior 2-kernel structure measured
// 56.3 us against a ~0.2 us memory-roofline floor -> dispatch-overhead
// bound. One cooperative launch replaces partial+final kernels.

namespace cg = cooperative_groups;

#define N_ROWS 1024
#define D 256
#define NBLK 64
#define ROWS_PER_BLK (N_ROWS / NBLK)   // 16
#define BETA 0.001f

// Block b handles rows [b*16, b*16+16); thread t = dim t.
// Coalesced: in each row pass, the 256 threads read one contiguous 1KB row.
// Partials: ws[b*512 + d] = sum, ws[b*512 + 256 + d] = sumsq. (128 KB)
// After grid.sync() (device-scope ordering -> safe across XCD L2s),
// block 0 folds the 64 partials and reduces to the scalar.
__global__ void club_fused(const float* __restrict__ y,
                           float* __restrict__ ws,
                           float* __restrict__ out) {
    const int d = threadIdx.x;                 // 0..255
    const int b = blockIdx.x;                  // 0..63

    // ---- phase 1: per-block per-dim sum / sumsq ----
    {
        const float* p = y + (size_t)b * ROWS_PER_BLK * D + d;
        float s = 0.f, s2 = 0.f;
#pragma unroll
        for (int r = 0; r < ROWS_PER_BLK; ++r) {
            float v = p[r * D];
            s  += v;
            s2 += v * v;
        }
        ws[b * (2 * D) + d]     = s;
        ws[b * (2 * D) + D + d] = s2;
    }

    // ---- grid-wide barrier (execution + memory visibility) ----
    cg::this_grid().sync();

    // ---- phase 2: block 0 folds partials -> variance -> scalar ----
    if (b == 0) {
        float s = 0.f, s2 = 0.f;
#pragma unroll 8
        for (int g = 0; g < NBLK; ++g) {
            s  += ws[g * (2 * D) + d];
            s2 += ws[g * (2 * D) + D + d];
        }
        const float invN = 1.0f / (float)N_ROWS;
        float mu = s * invN;
        float v  = s2 * invN - mu * mu;   // per-dim variance contribution

        // wave(64)-level shuffle reduction
#pragma unroll
        for (int off = 32; off > 0; off >>= 1)
            v += __shfl_down(v, off, 64);

        __shared__ float lds[4];
        const int wave = threadIdx.x >> 6;
        const int lane = threadIdx.x & 63;
        if (lane == 0) lds[wave] = v;
        __syncthreads();
        if (threadIdx.x == 0) {
            float t = lds[0] + lds[1] + lds[2] + lds[3];
            out[0] = t * BETA;
        }
    }
}

extern "C" void kernel_launch(void* const* d_in, const int* in_sizes, int n_in,
                              void* d_out, int out_size, void* d_ws, size_t ws_size,
                              hipStream_t stream) {
    const float* y = (const float*)d_in[0];
    float* ws = (float*)d_ws;          // needs NBLK*2*D*4 = 128 KB
    float* out = (float*)d_out;

    void* args[] = { (void*)&y, (void*)&ws, (void*)&out };
    hipLaunchCooperativeKernel((const void*)club_fused,
                               dim3(NBLK), dim3(D), args, 0, stream);
}

// Round 2
// 56.720 us; speedup vs baseline: 1.4112x; 1.4112x over previous
//
#include <hip/hip_runtime.h>

// mi = BETA * sum_d ( E[y_d^2] - (E[y_d])^2 )  over y: [1024, 256] fp32.
// Derivation: mean_i mean_j (y_jd - y_id)^2 = 2*Var_d; the /2 cancels.
//
// Timing structure (from rocprof round 1): every iteration pays a fixed
// ~41 us harness poison-fill of the 256 MB workspace (HBM-roofline, not
// ours). The only controllable cost is dispatch count x overhead.
// -> ONE regular (graph-capturable) kernel launch. Cooperative launch
//    measured ~39 us of overhead; regular kernel ~7 us.
//
// Fusion without zero-init (ws is POISONED each iteration, so no atomic
// counter): init-free done-flag protocol.
//   block b in [1,16): write per-dim partials -> __threadfence (agent
//     release, covers cross-XCD L2) -> store MAGIC to flags[b].
//   block 0: computes its own partial, spin-reads flags[1..15] with
//     agent-scope acquire loads (one flag per thread, parallel), fence,
//     folds 16x512 floats, block-reduces, writes out.
// Poison resets flags every iteration; MAGIC != any plausible poison
// pattern. 16 blocks << 256 CUs -> all co-resident, no spin deadlock.

#define N_ROWS 1024
#define D 256
#define NBLK 16
#define ROWS_PER_BLK (N_ROWS / NBLK)   // 64
#define BETA 0.001f
#define MAGIC 0x9E3779B97F4A7C15ULL

__global__ __launch_bounds__(256)
void club_onepass(const float* __restrict__ y,
                  float* __restrict__ ws,
                  float* __restrict__ out) {
    const int d = threadIdx.x;                 // 0..255
    const int b = blockIdx.x;                  // 0..15
    unsigned long long* flags =
        (unsigned long long*)(ws + NBLK * 2 * D);   // at +32 KB, 8-aligned

    // ---- phase 1: per-block per-dim sum / sumsq (coalesced row reads) ----
    {
        const float* p = y + (size_t)b * ROWS_PER_BLK * D + d;
        float s = 0.f, s2 = 0.f;
#pragma unroll 16
        for (int r = 0; r < ROWS_PER_BLK; ++r) {
            float v = p[(size_t)r * D];
            s  += v;
            s2 += v * v;
        }
        ws[b * (2 * D) + d]     = s;
        ws[b * (2 * D) + D + d] = s2;
    }

    if (b != 0) {
        // publish: every thread fences its own partial stores (agent scope),
        // barrier orders the fences before thread 0's flag store.
        __threadfence();
        __syncthreads();
        if (threadIdx.x == 0)
            __hip_atomic_store(&flags[b], (unsigned long long)MAGIC,
                               __ATOMIC_RELEASE, __HIP_MEMORY_SCOPE_AGENT);
        return;
    }

    // ---- finisher: block 0 ----
    // parallel spin: thread t waits on flags[t], t = 1..15
    if (threadIdx.x >= 1 && threadIdx.x < NBLK) {
        while (__hip_atomic_load(&flags[threadIdx.x], __ATOMIC_ACQUIRE,
                                 __HIP_MEMORY_SCOPE_AGENT) != MAGIC) { }
    }
    __syncthreads();
    __threadfence();   // acquire side: invalidate stale L1/L2 before partial reads

    float S = 0.f, S2 = 0.f;
#pragma unroll
    for (int g = 0; g < NBLK; ++g) {
        S  += ws[g * (2 * D) + d];
        S2 += ws[g * (2 * D) + D + d];
    }
    const float invN = 1.0f / (float)N_ROWS;
    float mu = S * invN;
    float v  = S2 * invN - mu * mu;   // per-dim variance contribution

    // wave(64)-level shuffle reduction
#pragma unroll
    for (int off = 32; off > 0; off >>= 1)
        v += __shfl_down(v, off, 64);

    __shared__ float lds[4];
    const int wave = threadIdx.x >> 6;
    const int lane = threadIdx.x & 63;
    if (lane == 0) lds[wave] = v;
    __syncthreads();
    if (threadIdx.x == 0) {
        float t = lds[0] + lds[1] + lds[2] + lds[3];
        out[0] = t * BETA;
    }
}

extern "C" void kernel_launch(void* const* d_in, const int* in_sizes, int n_in,
                              void* d_out, int out_size, void* d_ws, size_t ws_size,
                              hipStream_t stream) {
    const float* y = (const float*)d_in[0];
    float* ws = (float*)d_ws;          // uses NBLK*2*D*4 + NBLK*8 = ~33 KB
    float* out = (float*)d_out;

    club_onepass<<<NBLK, D, 0, stream>>>(y, ws, out);
}